// Round 3
// baseline (282.757 us; speedup 1.0000x reference)
//
#include <hip/hip_runtime.h>

#define BT_ROWS 65536      // 8*8192 rows
#define DIM     512
#define NK      32
#define TPB     256
#define RPB     64                     // rows per block (4 waves x 16 rows)
#define NBLK    (BT_ROWS / RPB)        // 1024 blocks -> 4 waves/SIMD
#define QDIM    (DIM / 4)              // 128 dims per quarter-thread

typedef float f4 __attribute__((ext_vector_type(4)));

// d_ws layout: float c2[NK] | float blockloss[NBLK] | int counts[NK]

__global__ void vq_prep(const float* __restrict__ cb, float* __restrict__ c2,
                        int* __restrict__ counts) {
    int t = threadIdx.x;
    if (t < NK) {
        const f4* c4 = (const f4*)(cb + t * DIM);
        float s = 0.f;
#pragma unroll 8
        for (int i = 0; i < DIM / 4; ++i) {
            f4 v = c4[i];
            s += v.x * v.x + v.y * v.y + v.z * v.z + v.w * v.w;
        }
        c2[t] = s;
    } else if (t < 2 * NK) {
        counts[t - NK] = 0;
    }
}

__global__ __launch_bounds__(TPB, 4) void vq_main(const float* __restrict__ x,
                                                  const float* __restrict__ cb,
                                                  const float* __restrict__ c2,
                                                  float* __restrict__ out,
                                                  float* __restrict__ blockloss,
                                                  int* __restrict__ counts) {
    const int tid  = threadIdx.x;
    const int lane = tid & 63;
    const int wv   = tid >> 6;        // wave 0..3
    const int q    = lane >> 4;       // quarter 0..3 (dims [q*128, q*128+128))
    const int r    = lane & 15;       // row-in-wave 0..15
    const int row  = blockIdx.x * RPB + wv * 16 + r;

    __shared__ float         wls[TPB / 64];
    __shared__ int           hist[NK];
    __shared__ unsigned char karr[RPB];
    if (tid < NK) hist[tid] = 0;

    float acc[NK];
#pragma unroll
    for (int k = 0; k < NK; ++k) acc[k] = 0.f;
    float x2 = 0.f;

    const f4* __restrict__ xr  = (const f4*)(x + (size_t)row * DIM + q * QDIM);
    const f4* __restrict__ cb4 = (const f4*)cb;

    // 4 chunks of 32 floats per quarter
#pragma unroll 2
    for (int c = 0; c < QDIM / 32; ++c) {
        f4 xv[8];
#pragma unroll
        for (int j = 0; j < 8; ++j) xv[j] = __builtin_nontemporal_load(xr + c * 8 + j);

#pragma unroll
        for (int j = 0; j < 8; ++j)
            x2 += xv[j].x * xv[j].x + xv[j].y * xv[j].y + xv[j].z * xv[j].z + xv[j].w * xv[j].w;

#pragma unroll
        for (int k = 0; k < NK; ++k) {
            // address uniform within each 16-lane quarter-group -> 4 segments/wave, L1-hot
            const f4* cp = cb4 + k * (DIM / 4) + q * (QDIM / 4) + c * 8;
            float s0 = 0.f, s1 = 0.f, s2 = 0.f, s3 = 0.f;
#pragma unroll
            for (int j = 0; j < 8; ++j) {
                f4 cv = cp[j];
                s0 += xv[j].x * cv.x;
                s1 += xv[j].y * cv.y;
                s2 += xv[j].z * cv.z;
                s3 += xv[j].w * cv.w;
            }
            acc[k] += (s0 + s1) + (s2 + s3);
        }
    }

    // combine the 4 quarter-partials: xor 16 merges q0<->q1,q2<->q3; xor 32 merges halves
#pragma unroll
    for (int k = 0; k < NK; ++k) {
        acc[k] += __shfl_xor(acc[k], 16, 64);
        acc[k] += __shfl_xor(acc[k], 32, 64);
    }
    x2 += __shfl_xor(x2, 16, 64);
    x2 += __shfl_xor(x2, 32, 64);

    // dist_k = (x2 + c2[k]) - 2*acc[k]; keep-first ties (ascending k) like np.argmin
    int   kmin = 0;
    float best = x2 + c2[0] - 2.f * acc[0];
#pragma unroll
    for (int k = 1; k < NK; ++k) {
        float d = x2 + c2[k] - 2.f * acc[k];
        if (d < best) { best = d; kmin = k; }
    }

    // best == ||q - x||^2 for this row; only quarter-0 lanes contribute to the sums
    float ls = (q == 0) ? best : 0.f;
#pragma unroll
    for (int m = 32; m; m >>= 1) ls += __shfl_xor(ls, m, 64);
    if (lane == 0) wls[wv] = ls;

    __syncthreads();   // hist zeroed + wls/karr ordering
    if (q == 0) {
        karr[wv * 16 + r] = (unsigned char)kmin;
        atomicAdd(&hist[kmin], 1);
    }
    __syncthreads();

    if (tid == 0) blockloss[blockIdx.x] = wls[0] + wls[1] + wls[2] + wls[3];
    if (tid < NK) {
        int h = hist[tid];
        if (h) atomicAdd(&counts[tid], h);
    }

    // cooperative coalesced q-write: wave wv writes its 16 rows, 1KB per store pass
    f4* __restrict__ o4 = (f4*)out;
    const size_t wrow0 = (size_t)blockIdx.x * RPB + (size_t)(wv << 4);
#pragma unroll 1
    for (int rr = 0; rr < 16; ++rr) {
        int    kr   = karr[(wv << 4) + rr];           // LDS broadcast, uniform per wave
        size_t base = (wrow0 + (size_t)rr) * (DIM / 4);
        f4 v0 = cb4[kr * (DIM / 4) + lane];
        f4 v1 = cb4[kr * (DIM / 4) + 64 + lane];
        __builtin_nontemporal_store(v0, o4 + base + lane);
        __builtin_nontemporal_store(v1, o4 + base + 64 + lane);
    }
}

__global__ void vq_final(const float* __restrict__ blockloss, const int* __restrict__ counts,
                         float* __restrict__ out) {
    int   t = threadIdx.x;      // 256 threads, NBLK = 1024
    float v = blockloss[t] + blockloss[t + 256] + blockloss[t + 512] + blockloss[t + 768];
#pragma unroll
    for (int m = 32; m; m >>= 1) v += __shfl_xor(v, m, 64);
    __shared__ float red[4];
    if ((t & 63) == 0) red[t >> 6] = v;
    __syncthreads();
    if (t == 0)
        out[(size_t)BT_ROWS * DIM] =
            1.25f * (red[0] + red[1] + red[2] + red[3]) / (float)((size_t)BT_ROWS * DIM);
    if (t < NK)
        out[(size_t)BT_ROWS * DIM + 1 + t] = (float)counts[t];
}

extern "C" void kernel_launch(void* const* d_in, const int* in_sizes, int n_in,
                              void* d_out, int out_size, void* d_ws, size_t ws_size,
                              hipStream_t stream) {
    const float* x  = (const float*)d_in[0];
    const float* cb = (const float*)d_in[1];
    float* out = (float*)d_out;

    float* c2        = (float*)d_ws;
    float* blockloss = c2 + NK;
    int*   counts    = (int*)(blockloss + NBLK);

    vq_prep<<<1, 64, 0, stream>>>(cb, c2, counts);
    vq_main<<<NBLK, TPB, 0, stream>>>(x, cb, c2, out, blockloss, counts);
    vq_final<<<1, 256, 0, stream>>>(blockloss, counts, out);
}